// Round 2
// baseline (444.736 us; speedup 1.0000x reference)
//
#include <hip/hip_runtime.h>
#include <cstdint>
#include <cstddef>

#define B_   2
#define S_   2048
#define H_   2048
#define NH_  16
#define HD_  128
#define MM_  (B_ * S_)          /* 4096 rows of x */
#define K_   H_                 /* 2048 reduction dim for projections */
#define SCALE_F 0.08838834764831845f

typedef __bf16 bf16_t;
typedef __attribute__((ext_vector_type(8))) __bf16 bf16x8;
typedef __attribute__((ext_vector_type(4))) float  f32x4;
typedef __attribute__((ext_vector_type(4))) float  floatx4;

static __device__ __forceinline__ f32x4 mfma_16x16x32(bf16x8 a, bf16x8 b, f32x4 c) {
  return __builtin_amdgcn_mfma_f32_16x16x32_bf16(a, b, c, 0, 0, 0);
}

static __device__ __forceinline__ void gl2lds16(const bf16_t* g, bf16_t* l) {
  __builtin_amdgcn_global_load_lds(
      (const __attribute__((address_space(1))) void*)g,
      (__attribute__((address_space(3))) void*)l, 16, 0, 0);
}

// ---------------------------------------------------------------- fp32->bf16
__global__ void cvt_f32_bf16(const float* __restrict__ in, bf16_t* __restrict__ out, int n8) {
  int i = blockIdx.x * blockDim.x + threadIdx.x;
  const int stride = gridDim.x * blockDim.x;
  for (; i < n8; i += stride) {
    const floatx4* p = (const floatx4*)(in + (size_t)i * 8);
    floatx4 a = p[0], b = p[1];
    bf16x8 o;
    o[0] = (bf16_t)a.x; o[1] = (bf16_t)a.y; o[2] = (bf16_t)a.z; o[3] = (bf16_t)a.w;
    o[4] = (bf16_t)b.x; o[5] = (bf16_t)b.y; o[6] = (bf16_t)b.z; o[7] = (bf16_t)b.w;
    *(bf16x8*)(out + (size_t)i * 8) = o;
  }
}

// 4 weight matrices in one launch (blockIdx.y selects)
__global__ void cvt4_f32_bf16(const float* __restrict__ i0, const float* __restrict__ i1,
                              const float* __restrict__ i2, const float* __restrict__ i3,
                              bf16_t* o0, bf16_t* o1, bf16_t* o2, bf16_t* o3, int n8) {
  const float* in = (blockIdx.y == 0) ? i0 : (blockIdx.y == 1) ? i1 : (blockIdx.y == 2) ? i2 : i3;
  bf16_t*      out = (blockIdx.y == 0) ? o0 : (blockIdx.y == 1) ? o1 : (blockIdx.y == 2) ? o2 : o3;
  int i = blockIdx.x * blockDim.x + threadIdx.x;
  const int stride = gridDim.x * blockDim.x;
  for (; i < n8; i += stride) {
    const floatx4* p = (const floatx4*)(in + (size_t)i * 8);
    floatx4 a = p[0], b = p[1];
    bf16x8 o;
    o[0] = (bf16_t)a.x; o[1] = (bf16_t)a.y; o[2] = (bf16_t)a.z; o[3] = (bf16_t)a.w;
    o[4] = (bf16_t)b.x; o[5] = (bf16_t)b.y; o[6] = (bf16_t)b.z; o[7] = (bf16_t)b.w;
    *(bf16x8*)(out + (size_t)i * 8) = o;
  }
}

// ------------------------------------------------------- GEMM C = A * B^T + b
// MODE 0: fused QKV. grid.y in [0,48): wsel=y>>4 picks W/bias/dst.
//   wsel 0/1 (Q,K): head-major [B*NH][S][HD] bf16.
//   wsel 2   (V)  : TRANSPOSED head-major [B*NH][HD][S] bf16 (for attn B-frag).
// MODE 1: O-projection, fp32 [M,H] + bias.
template <int MODE>
__global__ __launch_bounds__(256) void gemm_bt(
    const bf16_t* __restrict__ A,
    const bf16_t* __restrict__ W0, const bf16_t* __restrict__ W1, const bf16_t* __restrict__ W2,
    const float* __restrict__ bias0, const float* __restrict__ bias1, const float* __restrict__ bias2,
    bf16_t* __restrict__ dq, bf16_t* __restrict__ dk, bf16_t* __restrict__ dv,
    float* __restrict__ outf)
{
  __shared__ __align__(16) bf16_t Ash[128 * 32];
  __shared__ __align__(16) bf16_t Bsh[128 * 32];

  const int t = threadIdx.x;
  const int lane = t & 63;
  const int wid  = t >> 6;
  const int wm = wid >> 1, wn = wid & 1;

  const int bm = blockIdx.x * 128;
  int bn;
  int wsel = 0;
  const bf16_t* Bw;
  const float*  bias;
  bf16_t* dsth = nullptr;
  if constexpr (MODE == 0) {
    wsel = blockIdx.y >> 4;
    bn   = (blockIdx.y & 15) * 128;
    Bw   = (wsel == 0) ? W0 : ((wsel == 1) ? W1 : W2);
    bias = (wsel == 0) ? bias0 : ((wsel == 1) ? bias1 : bias2);
    dsth = (wsel == 0) ? dq : ((wsel == 1) ? dk : dv);
  } else {
    bn = blockIdx.y * 128;
    Bw = W0; bias = bias0;
  }

  const bf16_t* gA = A  + (size_t)(bm + (t >> 2)) * K_ + (t & 3) * 8;
  const bf16_t* gB = Bw + (size_t)(bn + (t >> 2)) * K_ + (t & 3) * 8;
  bf16_t* lA = Ash + wid * 512;
  bf16_t* lB = Bsh + wid * 512;

  f32x4 acc[4][4] = {};

  #pragma unroll 1
  for (int k0 = 0; k0 < K_; k0 += 32) {
    gl2lds16(gA + k0,                    lA);
    gl2lds16(gA + k0 + (size_t)64 * K_,  lA + 2048);
    gl2lds16(gB + k0,                    lB);
    gl2lds16(gB + k0 + (size_t)64 * K_,  lB + 2048);
    __syncthreads();

    bf16x8 af[4], bfr[4];
    #pragma unroll
    for (int i = 0; i < 4; ++i) {
      af[i]  = *(const bf16x8*)&Ash[(wm * 64 + i * 16 + (lane & 15)) * 32 + (lane >> 4) * 8];
      bfr[i] = *(const bf16x8*)&Bsh[(wn * 64 + i * 16 + (lane & 15)) * 32 + (lane >> 4) * 8];
    }
    __builtin_amdgcn_s_setprio(1);
    #pragma unroll
    for (int i = 0; i < 4; ++i)
      #pragma unroll
      for (int j = 0; j < 4; ++j)
        acc[i][j] = mfma_16x16x32(af[i], bfr[j], acc[i][j]);
    __builtin_amdgcn_s_setprio(0);
    __syncthreads();
  }

  // epilogue. C/D frag: col = lane&15, row = (lane>>4)*4 + r
  const int row0 = bm + wm * 64 + (lane >> 4) * 4;
  const int col0 = bn + wn * 64 + (lane & 15);
  #pragma unroll
  for (int j = 0; j < 4; ++j) {
    const int col = col0 + j * 16;
    const float bv = bias[col];
    #pragma unroll
    for (int i = 0; i < 4; ++i) {
      #pragma unroll
      for (int r = 0; r < 4; ++r) {
        const int row = row0 + i * 16 + r;
        const float v = acc[i][j][r] + bv;
        if constexpr (MODE == 0) {
          const int bb = row >> 11, ss = row & (S_ - 1);
          const int hh = col >> 7,  dd = col & (HD_ - 1);
          if (wsel == 2) {
            // V^T: [bh][d][S]
            dsth[((size_t)((bb * NH_ + hh) * HD_ + dd)) * S_ + ss] = (bf16_t)v;
          } else {
            dsth[((((size_t)bb * NH_) + hh) * S_ + ss) * HD_ + dd] = (bf16_t)v;
          }
        } else {
          outf[(size_t)row * H_ + col] = v;
        }
      }
    }
  }
}

// ------------------------------------------------------------ flash attention
// grid: 512 blocks (XCD-swizzled -> head = wg>>4, qtile = wg&15).
// 4 waves x 32 q-rows. KV tile = 64, double-buffered K + V^T in LDS via
// global_load_lds with pre-swizzled source; XOR-swizzled ds_read_b128.
#define KVB 64
#define NT_ (S_ / KVB)

__global__ __launch_bounds__(256) void attn_kernel(
    const bf16_t* __restrict__ Qh, const bf16_t* __restrict__ Kh,
    const bf16_t* __restrict__ Vtg, const float* __restrict__ mask,
    bf16_t* __restrict__ ctx)
{
  __shared__ __align__(16) bf16_t Klds[2][KVB * HD_];   // [kv][d] linear, swz reads
  __shared__ __align__(16) bf16_t Vlds[2][HD_ * KVB];   // [d][kv] linear, swz reads
  __shared__ __align__(16) bf16_t Plds[4][32 * KVB];    // per-wave P bounce, swz

  const int t = threadIdx.x;
  const int lane = t & 63;
  const int wid  = t >> 6;

  // XCD swizzle: 512 blocks, 8 XCDs -> 64 contiguous wg per XCD (4 heads each)
  const int orig = blockIdx.x;
  const int wg = (orig & 7) * 64 + (orig >> 3);
  const int qt = wg & 15;
  const int bh = wg >> 4;
  const int b  = bh >> 4;
  const int h  = bh & 15;
  const int q0 = qt * 128 + wid * 32;

  const bf16_t* Qb = Qh + (size_t)bh * S_ * HD_ + (size_t)q0 * HD_;
  const bf16_t* Kg = Kh + (size_t)bh * S_ * HD_;
  const bf16_t* Vg = Vtg + (size_t)bh * HD_ * S_;

  // Q fragments in registers: A-frag row = lane&15, k = (lane>>4)*8 + j
  bf16x8 qf[2][4];
  #pragma unroll
  for (int mh = 0; mh < 2; ++mh)
    #pragma unroll
    for (int ks = 0; ks < 4; ++ks)
      qf[mh][ks] = *(const bf16x8*)&Qb[(size_t)(mh * 16 + (lane & 15)) * HD_ + ks * 32 + (lane >> 4) * 8];

  f32x4 acc[2][8] = {};
  float m_run[2][4], l_run[2][4];
  #pragma unroll
  for (int mh = 0; mh < 2; ++mh)
    #pragma unroll
    for (int r = 0; r < 4; ++r) { m_run[mh][r] = -INFINITY; l_run[mh][r] = 0.0f; }

  char* Pw = (char*)&Plds[wid][0];

  // --- staging: K tile 64x128 (1024 x 16B chunks), V^T tile 128x64 (1024)
  auto stage = [&](int it, int buf) {
    const int kv0 = it * KVB;
    #pragma unroll
    for (int j = 0; j < 4; ++j) {
      const int bc = (wid * 4 + j) * 64;          // wave-uniform chunk base
      const int c  = bc + lane;
      const int row = c >> 4;                      // kv row 0..63
      const int col8 = (c & 15) ^ (row & 7);       // pre-swizzled source
      gl2lds16(Kg + (size_t)(kv0 + row) * HD_ + col8 * 8, &Klds[buf][bc * 8]);
    }
    #pragma unroll
    for (int j = 0; j < 4; ++j) {
      const int bc = (wid * 4 + j) * 64;
      const int c  = bc + lane;
      const int d  = c >> 3;                       // d row 0..127
      const int col8 = (c & 7) ^ (d & 7);
      gl2lds16(Vg + (size_t)d * S_ + kv0 + col8 * 8, &Vlds[buf][bc * 8]);
    }
  };

  stage(0, 0);

  #pragma unroll 1
  for (int it = 0; it < NT_; ++it) {
    __syncthreads();             // drains vmcnt: tile `it` ready; prev reads done
    const int buf = it & 1;
    if (it + 1 < NT_) stage(it + 1, buf ^ 1);

    const char* Kb = (const char*)&Klds[buf][0];
    const char* Vb = (const char*)&Vlds[buf][0];
    const int kv0 = it * KVB;

    // ---- S = Q K^T
    f32x4 sacc[2][4] = {};
    #pragma unroll
    for (int ns = 0; ns < 4; ++ns) {
      const int krow = ns * 16 + (lane & 15);
      #pragma unroll
      for (int ks = 0; ks < 4; ++ks) {
        const int kb = (krow << 8) + ((((ks << 6) | ((lane >> 4) << 4))) ^ ((krow & 7) << 4));
        const bf16x8 kf = *(const bf16x8*)(Kb + kb);
        __builtin_amdgcn_s_setprio(1);
        sacc[0][ns] = mfma_16x16x32(qf[0][ks], kf, sacc[0][ns]);
        sacc[1][ns] = mfma_16x16x32(qf[1][ks], kf, sacc[1][ns]);
        __builtin_amdgcn_s_setprio(0);
      }
    }

    float msk[4];
    #pragma unroll
    for (int ns = 0; ns < 4; ++ns)
      msk[ns] = mask[(size_t)b * S_ + kv0 + ns * 16 + (lane & 15)];

    // ---- online softmax. D-frag: col(kk)=lane&15, row(q)=(lane>>4)*4+r
    #pragma unroll
    for (int mh = 0; mh < 2; ++mh) {
      float sv[4][4];
      float tmax[4] = {-INFINITY, -INFINITY, -INFINITY, -INFINITY};
      #pragma unroll
      for (int ns = 0; ns < 4; ++ns)
        #pragma unroll
        for (int r = 0; r < 4; ++r) {
          sv[ns][r] = sacc[mh][ns][r] * SCALE_F + msk[ns];
          tmax[r] = fmaxf(tmax[r], sv[ns][r]);
        }
      #pragma unroll
      for (int off = 1; off < 16; off <<= 1)
        #pragma unroll
        for (int r = 0; r < 4; ++r)
          tmax[r] = fmaxf(tmax[r], __shfl_xor(tmax[r], off));

      float scl[4], rsum[4];
      #pragma unroll
      for (int r = 0; r < 4; ++r) {
        const float mnew = fmaxf(m_run[mh][r], tmax[r]);
        scl[r] = __expf(m_run[mh][r] - mnew);
        m_run[mh][r] = mnew;
        rsum[r] = 0.0f;
      }
      #pragma unroll
      for (int ns = 0; ns < 4; ++ns)
        #pragma unroll
        for (int r = 0; r < 4; ++r) {
          const float p = __expf(sv[ns][r] - m_run[mh][r]);
          rsum[r] += p;
          const int qq = mh * 16 + (lane >> 4) * 4 + r;
          const int pb = (qq << 7) + ((((ns << 5) | ((lane & 15) << 1))) ^ ((qq & 7) << 4));
          *(bf16_t*)(Pw + pb) = (bf16_t)p;
        }
      #pragma unroll
      for (int off = 1; off < 16; off <<= 1)
        #pragma unroll
        for (int r = 0; r < 4; ++r)
          rsum[r] += __shfl_xor(rsum[r], off);
      #pragma unroll
      for (int r = 0; r < 4; ++r)
        l_run[mh][r] = l_run[mh][r] * scl[r] + rsum[r];
      #pragma unroll
      for (int ds = 0; ds < 8; ++ds)
        #pragma unroll
        for (int r = 0; r < 4; ++r)
          acc[mh][ds][r] *= scl[r];
    }

    // ---- ctx += P * V  (A=P bounce, B=V^T staged)
    bf16x8 pf[2][2];
    #pragma unroll
    for (int mh = 0; mh < 2; ++mh)
      #pragma unroll
      for (int k2 = 0; k2 < 2; ++k2) {
        const int qq = mh * 16 + (lane & 15);
        const int pb = (qq << 7) + (((k2 << 6) | ((lane >> 4) << 4)) ^ ((qq & 7) << 4));
        pf[mh][k2] = *(const bf16x8*)(Pw + pb);
      }

    #pragma unroll
    for (int ds = 0; ds < 8; ++ds) {
      const int d = ds * 16 + (lane & 15);
      const int vb0 = (d << 7) + ((((lane >> 4) << 4)) ^ ((d & 7) << 4));
      const int vb1 = (d << 7) + (((64) | ((lane >> 4) << 4)) ^ ((d & 7) << 4));
      const bf16x8 vf0 = *(const bf16x8*)(Vb + vb0);
      const bf16x8 vf1 = *(const bf16x8*)(Vb + vb1);
      __builtin_amdgcn_s_setprio(1);
      #pragma unroll
      for (int mh = 0; mh < 2; ++mh) {
        acc[mh][ds] = mfma_16x16x32(pf[mh][0], vf0, acc[mh][ds]);
        acc[mh][ds] = mfma_16x16x32(pf[mh][1], vf1, acc[mh][ds]);
      }
      __builtin_amdgcn_s_setprio(0);
    }
  }

  // normalize + write ctx [B,S,H] bf16 for O-projection
  #pragma unroll
  for (int mh = 0; mh < 2; ++mh)
    #pragma unroll
    for (int ds = 0; ds < 8; ++ds)
      #pragma unroll
      for (int r = 0; r < 4; ++r) {
        const int q = q0 + mh * 16 + (lane >> 4) * 4 + r;
        const int d = ds * 16 + (lane & 15);
        ctx[((size_t)(b * S_ + q)) * H_ + h * HD_ + d] =
            (bf16_t)(acc[mh][ds][r] / l_run[mh][r]);
      }
}

// ---------------------------------------------------------------------- host
extern "C" void kernel_launch(void* const* d_in, const int* in_sizes, int n_in,
                              void* d_out, int out_size, void* d_ws, size_t ws_size,
                              hipStream_t stream) {
  (void)in_sizes; (void)n_in; (void)out_size; (void)ws_size;
  const float* x    = (const float*)d_in[0];
  const float* mask = (const float*)d_in[1];
  const float* Wq   = (const float*)d_in[2];
  const float* bq   = (const float*)d_in[3];
  const float* Wk   = (const float*)d_in[4];
  const float* bk   = (const float*)d_in[5];
  const float* Wv   = (const float*)d_in[6];
  const float* bv   = (const float*)d_in[7];
  const float* Wo   = (const float*)d_in[8];
  const float* bo   = (const float*)d_in[9];
  float* out = (float*)d_out;

  const size_t nX = (size_t)MM_ * H_;
  const size_t nW = (size_t)H_ * H_;

  bf16_t* xbf = (bf16_t*)d_ws;
  bf16_t* wqb = xbf + nX;
  bf16_t* wkb = wqb + nW;
  bf16_t* wvb = wkb + nW;
  bf16_t* wob = wvb + nW;
  bf16_t* qh  = wob + nW;
  bf16_t* kh  = qh + nX;
  bf16_t* vt  = kh + nX;   // V^T head-major [B*NH][HD][S]
  bf16_t* cxb = vt + nX;

  cvt_f32_bf16<<<2048, 256, 0, stream>>>(x, xbf, (int)(nX / 8));
  cvt4_f32_bf16<<<dim3(1024, 4), 256, 0, stream>>>(Wq, Wk, Wv, Wo, wqb, wkb, wvb, wob, (int)(nW / 8));

  gemm_bt<0><<<dim3(MM_ / 128, 48), 256, 0, stream>>>(
      xbf, wqb, wkb, wvb, bq, bk, bv, qh, kh, vt, nullptr);

  attn_kernel<<<512, 256, 0, stream>>>(qh, kh, vt, mask, cxb);

  gemm_bt<1><<<dim3(MM_ / 128, H_ / 128), 256, 0, stream>>>(
      cxb, wob, nullptr, nullptr, bo, nullptr, nullptr, nullptr, nullptr, nullptr, out);
}